// Round 8
// baseline (223.456 us; speedup 1.0000x reference)
//
#include <hip/hip_runtime.h>
#include <math.h>

// CRDLoss on MI355X.
// Phase 0: convert W_s/W_t -> fp16 in ws (1 MB, L2-resident thereafter).
// Phase 1: embed GEMM 8192x2048x128 + bias + L2-norm -> fp16 embeddings.
//          R8: BK=128 (16 iters, half the barrier stalls), 16-row tiles,
//          grid (512,2) = 2 blocks/CU, XOR-swizzled unpadded LDS (loss-proven),
//          per-block K phase stagger to decorrelate barrier stalls.
// Phase 2: 8192x8192 similarity via f16 MFMA, fused exp/log epilogue (proven).
// Phase 3: reduce 4096 partials -> out[0] = -(sum)/B.

typedef _Float16 half_t;
typedef half_t halfx4 __attribute__((ext_vector_type(4)));
typedef half_t halfx8 __attribute__((ext_vector_type(8)));
typedef float f32x4 __attribute__((ext_vector_type(4)));

#define B_TOT   8192
#define K_EMB   2048
#define F_DIM   128
#define INV_T   14.285714285714286f   // 1/0.07
#define EPS_C   0.97f
#define LOG_EPS (-0.030459207485f)    // ln(0.97)

// ---------------------------------------------------------------------------
// W fp32 -> fp16.  grid = (256, 2); block = 256; one float4 per thread.
// ---------------------------------------------------------------------------
__global__ __launch_bounds__(256) void cvt_w_kernel(
    const float* __restrict__ Ws, const float* __restrict__ Wt,
    half_t* __restrict__ Ws16, half_t* __restrict__ Wt16)
{
    const float* src = blockIdx.y ? Wt : Ws;
    half_t* dst = blockIdx.y ? Wt16 : Ws16;
    int pos4 = blockIdx.x * 256 + threadIdx.x;      // 0..65535
    float4 v = *(const float4*)(src + (size_t)pos4 * 4);
    halfx4 h4 = {(half_t)v.x, (half_t)v.y, (half_t)v.z, (half_t)v.w};
    *(halfx4*)(dst + (size_t)pos4 * 4) = h4;
}

// ---------------------------------------------------------------------------
// Embed: 16-row tile x 128 cols, BK=128, double-buffered, XOR-swizzled LDS.
// grid = (512, 2); block = 256 (4 waves, each: all 16 rows x 32 cols).
// ---------------------------------------------------------------------------
__global__ __launch_bounds__(256) void embed_kernel(
    const float* __restrict__ Xs, const float* __restrict__ Xt,
    const half_t* __restrict__ Ws16, const half_t* __restrict__ Wt16,
    const float* __restrict__ bs, const float* __restrict__ bt,
    half_t* __restrict__ outs, half_t* __restrict__ outt)
{
    const float* X; const half_t* W16; const float* bias; half_t* out;
    if (blockIdx.y == 0) { X = Xs; W16 = Ws16; bias = bs; out = outs; }
    else                 { X = Xt; W16 = Wt16; bias = bt; out = outt; }

    // unpadded, 16B-chunk XOR swizzle: phys = row*16 + (c ^ (row & 15))
    __shared__ uint4 As4[2][16 * 16];    //  8 KB: 16 rows x 128 k halves
    __shared__ uint4 Bs4[2][128 * 16];   // 64 KB: 128 cols x 128 k halves
    __shared__ float biasS[128];
    __shared__ float redS[16][4];
    __shared__ float invS[16];

    const int tid = threadIdx.x;
    const int r0  = blockIdx.x * 16;
    if (tid < 128) biasS[tid] = bias[tid];

    const int lane = tid & 63;
    const int w    = tid >> 6;           // wave 0..3 -> cols w*32
    const int l16  = lane & 15, lhi = lane >> 4;

    // K phase stagger: neighbor blocks start at different K chunks
    const int ph = (blockIdx.x & 1) * 8;

    f32x4 acc[2];
    acc[0] = f32x4{0.f, 0.f, 0.f, 0.f};
    acc[1] = f32x4{0.f, 0.f, 0.f, 0.f};

    // A staging: 256 chunks -> 1/thread.  row = tid>>4, c = tid&15.
    const int arow = tid >> 4, ac = tid & 15;
    // B staging: 2048 chunks -> 8/thread. g = tid + i*256: col = g>>4, c = g&15.

    float4 na0, na1; uint4 nb[8];

    // prologue: chunk ph into buffer 0
    {
        const int kb = ph * 128;
        na0 = *(const float4*)(X + (size_t)(r0 + arow) * K_EMB + kb + ac * 8);
        na1 = *(const float4*)(X + (size_t)(r0 + arow) * K_EMB + kb + ac * 8 + 4);
#pragma unroll
        for (int i = 0; i < 8; ++i) {
            int g = tid + i * 256;
            nb[i] = *(const uint4*)(W16 + (size_t)(g >> 4) * K_EMB + kb + (g & 15) * 8);
        }
        halfx8 h8 = {(half_t)na0.x, (half_t)na0.y, (half_t)na0.z, (half_t)na0.w,
                     (half_t)na1.x, (half_t)na1.y, (half_t)na1.z, (half_t)na1.w};
        *(halfx8*)&As4[0][arow * 16 + (ac ^ arow)] = h8;
#pragma unroll
        for (int i = 0; i < 8; ++i) {
            int g = tid + i * 256;
            Bs4[0][(g >> 4) * 16 + ((g & 15) ^ ((g >> 4) & 15))] = nb[i];
        }
    }
    __syncthreads();

    for (int it = 0; it < 16; ++it) {
        const int cur = it & 1;
        if (it < 15) {
            const int kb = (((it + 1 + ph) & 15)) * 128;
            na0 = *(const float4*)(X + (size_t)(r0 + arow) * K_EMB + kb + ac * 8);
            na1 = *(const float4*)(X + (size_t)(r0 + arow) * K_EMB + kb + ac * 8 + 4);
#pragma unroll
            for (int i = 0; i < 8; ++i) {
                int g = tid + i * 256;
                nb[i] = *(const uint4*)(W16 + (size_t)(g >> 4) * K_EMB + kb + (g & 15) * 8);
            }
        }
#pragma unroll
        for (int kk = 0; kk < 4; ++kk) {
            halfx8 a, b[2];
            a = *(const halfx8*)&As4[cur][l16 * 16 + ((kk * 4 + lhi) ^ l16)];
#pragma unroll
            for (int in = 0; in < 2; ++in) {
                int r = w * 32 + in * 16 + l16;
                b[in] = *(const halfx8*)&Bs4[cur][r * 16 + ((kk * 4 + lhi) ^ l16)];
            }
#pragma unroll
            for (int in = 0; in < 2; ++in)
                acc[in] = __builtin_amdgcn_mfma_f32_16x16x32_f16(a, b[in], acc[in], 0, 0, 0);
        }
        if (it < 15) {
            const int nxt = cur ^ 1;
            halfx8 h8 = {(half_t)na0.x, (half_t)na0.y, (half_t)na0.z, (half_t)na0.w,
                         (half_t)na1.x, (half_t)na1.y, (half_t)na1.z, (half_t)na1.w};
            *(halfx8*)&As4[nxt][arow * 16 + (ac ^ arow)] = h8;
#pragma unroll
            for (int i = 0; i < 8; ++i) {
                int g = tid + i * 256;
                Bs4[nxt][(g >> 4) * 16 + ((g & 15) ^ ((g >> 4) & 15))] = nb[i];
            }
        }
        __syncthreads();
    }

    // epilogue: +bias, row sum-of-squares (this wave's 32 cols), normalize
    float h[2][4];
    float psum[4];
#pragma unroll
    for (int reg = 0; reg < 4; ++reg) {
        float p = 0.f;
#pragma unroll
        for (int in = 0; in < 2; ++in) {
            int col = w * 32 + in * 16 + l16;
            float v = acc[in][reg] + biasS[col];
            h[in][reg] = v;
            p += v * v;
        }
        p += __shfl_xor(p, 1);
        p += __shfl_xor(p, 2);
        p += __shfl_xor(p, 4);
        p += __shfl_xor(p, 8);
        psum[reg] = p;
    }
    if (l16 == 0)
#pragma unroll
        for (int reg = 0; reg < 4; ++reg)
            redS[lhi * 4 + reg][w] = psum[reg];
    __syncthreads();
    if (tid < 16)
        invS[tid] = rsqrtf(redS[tid][0] + redS[tid][1] + redS[tid][2] + redS[tid][3]);
    __syncthreads();

#pragma unroll
    for (int in = 0; in < 2; ++in)
#pragma unroll
        for (int reg = 0; reg < 4; ++reg) {
            int row = lhi * 4 + reg;
            int col = w * 32 + in * 16 + l16;
            out[(size_t)(r0 + row) * F_DIM + col] = (half_t)(h[in][reg] * invS[row]);
        }
}

// ---------------------------------------------------------------------------
// Loss: 128x128 tile of fs·ft^T, K=128 in two 64-wide LDS chunks (33 KB LDS).
// grid = (64, 64); block = 256.  (unchanged, proven)
// ---------------------------------------------------------------------------
__global__ __launch_bounds__(256) void loss_kernel(
    const half_t* __restrict__ FS, const half_t* __restrict__ FT,
    const int* __restrict__ y, double* __restrict__ partials)
{
    __shared__ uint4 As4[128 * 8];   // 16 KB
    __shared__ uint4 Bs4[128 * 8];   // 16 KB
    __shared__ int   yrl[128], ycl[128];
    __shared__ float wsum[4];

    const int tid = threadIdx.x;
    const int i0  = blockIdx.x * 128;
    const int j0  = blockIdx.y * 128;

    if (tid < 128) yrl[tid] = y[i0 + tid];
    else           ycl[tid - 128] = y[j0 + tid - 128];

    const int lane = tid & 63;
    const int w    = tid >> 6;
    const int wm   = w >> 1, wn = w & 1;
    const int l16  = lane & 15, lhi = lane >> 4;

#pragma unroll
    for (int i = 0; i < 4; ++i) {
        int f = tid + i * 256;
        int row = f >> 3, c = f & 7;
        As4[row * 8 + (c ^ (row & 7))] = *(const uint4*)(FS + (size_t)(i0 + row) * F_DIM + c * 8);
    }
#pragma unroll
    for (int i = 0; i < 4; ++i) {
        int f = tid + i * 256;
        int row = f >> 3, c = f & 7;
        Bs4[row * 8 + (c ^ (row & 7))] = *(const uint4*)(FT + (size_t)(j0 + row) * F_DIM + c * 8);
    }
    __syncthreads();

    f32x4 acc[4][4];
    for (int im = 0; im < 4; ++im)
        for (int in = 0; in < 4; ++in)
            acc[im][in] = f32x4{0.f, 0.f, 0.f, 0.f};

    for (int kc = 0; kc < 2; ++kc) {
#pragma unroll
        for (int kk = 0; kk < 2; ++kk) {
            halfx8 a[4], b[4];
#pragma unroll
            for (int im = 0; im < 4; ++im) {
                int r = wm * 64 + im * 16 + l16;
                a[im] = *(const halfx8*)&As4[r * 8 + ((kk * 4 + lhi) ^ (r & 7))];
            }
#pragma unroll
            for (int in = 0; in < 4; ++in) {
                int r = wn * 64 + in * 16 + l16;
                b[in] = *(const halfx8*)&Bs4[r * 8 + ((kk * 4 + lhi) ^ (r & 7))];
            }
#pragma unroll
            for (int im = 0; im < 4; ++im)
#pragma unroll
                for (int in = 0; in < 4; ++in)
                    acc[im][in] = __builtin_amdgcn_mfma_f32_16x16x32_f16(
                        a[im], b[in], acc[im][in], 0, 0, 0);
        }
        if (kc == 0) {
            __syncthreads();
#pragma unroll
            for (int i = 0; i < 4; ++i) {
                int f = tid + i * 256;
                int row = f >> 3, c = f & 7;
                As4[row * 8 + (c ^ (row & 7))] =
                    *(const uint4*)(FS + (size_t)(i0 + row) * F_DIM + 64 + c * 8);
            }
#pragma unroll
            for (int i = 0; i < 4; ++i) {
                int f = tid + i * 256;
                int row = f >> 3, c = f & 7;
                Bs4[row * 8 + (c ^ (row & 7))] =
                    *(const uint4*)(FT + (size_t)(j0 + row) * F_DIM + 64 + c * 8);
            }
            __syncthreads();
        }
    }

    float local = 0.f;
    for (int im = 0; im < 4; ++im) {
        for (int reg = 0; reg < 4; ++reg) {
            int il = wm * 64 + im * 16 + lhi * 4 + reg;
            int yi = yrl[il];
            int gi = i0 + il;
            for (int in = 0; in < 4; ++in) {
                int jl = wn * 64 + in * 16 + l16;
                float s  = acc[im][in][reg];
                float sT = s * INV_T;
                float e  = __expf(sT);
                float l  = __logf(e + EPS_C);
                float term = (yi == ycl[jl]) ? (sT - l) : (LOG_EPS - l);
                if (gi != (j0 + jl)) local += term;
            }
        }
    }
    for (int m = 1; m < 64; m <<= 1) local += __shfl_xor(local, m);
    if (lane == 0) wsum[w] = local;
    __syncthreads();
    if (tid == 0)
        partials[blockIdx.y * gridDim.x + blockIdx.x] =
            ((double)wsum[0] + (double)wsum[1]) + ((double)wsum[2] + (double)wsum[3]);
}

// ---------------------------------------------------------------------------
__global__ __launch_bounds__(256) void finalize_kernel(
    const double* __restrict__ partials, float* __restrict__ out)
{
    __shared__ double sh[4];
    double loc = 0.0;
    for (int i = threadIdx.x; i < 4096; i += 256) loc += partials[i];
    for (int m = 1; m < 64; m <<= 1) loc += __shfl_xor(loc, m);
    int lane = threadIdx.x & 63, w = threadIdx.x >> 6;
    if (lane == 0) sh[w] = loc;
    __syncthreads();
    if (threadIdx.x == 0)
        out[0] = (float)(-(sh[0] + sh[1] + sh[2] + sh[3]) / (double)B_TOT);
}

// ---------------------------------------------------------------------------
extern "C" void kernel_launch(void* const* d_in, const int* in_sizes, int n_in,
                              void* d_out, int out_size, void* d_ws, size_t ws_size,
                              hipStream_t stream)
{
    // ws layout: [partials 32KB | pad->64KB | fs 2MB | ft 2MB | Ws16 512KB | Wt16 512KB]
    const size_t WS_NEEDED = (64 << 10) + (4 << 20) + (1 << 20);
    if (ws_size < WS_NEEDED) return;   // readable failure instead of OOB fault

    const float* f_s = (const float*)d_in[0];
    const float* f_t = (const float*)d_in[1];
    const int*   y   = (const int*)d_in[2];
    const float* W_s = (const float*)d_in[3];
    const float* b_s = (const float*)d_in[4];
    const float* W_t = (const float*)d_in[5];
    const float* b_t = (const float*)d_in[6];
    float* out = (float*)d_out;

    char* ws = (char*)d_ws;
    double* partials = (double*)ws;                               // 32 KB
    half_t* fs   = (half_t*)(ws + (64 << 10));                    // 2 MB
    half_t* ft   = (half_t*)(ws + (64 << 10) + (2 << 20));        // 2 MB
    half_t* Ws16 = (half_t*)(ws + (64 << 10) + (4 << 20));        // 512 KB
    half_t* Wt16 = (half_t*)(ws + (64 << 10) + (4 << 20) + (512 << 10));

    cvt_w_kernel<<<dim3(256, 2), 256, 0, stream>>>(W_s, W_t, Ws16, Wt16);
    embed_kernel<<<dim3(512, 2), 256, 0, stream>>>(f_s, f_t, Ws16, Wt16, b_s, b_t, fs, ft);
    loss_kernel<<<dim3(64, 64), 256, 0, stream>>>(fs, ft, y, partials);
    finalize_kernel<<<1, 256, 0, stream>>>(partials, out);
    (void)in_sizes; (void)n_in; (void)out_size;
}